// Round 10
// baseline (163.297 us; speedup 1.0000x reference)
//
#include <hip/hip_runtime.h>
#include <hip/hip_bf16.h>

#define RSH 7                  // 128 rows per bucket
#define RPB (1 << RSH)
#define CSH 17                 // col bits in packed record (N < 131072)
#define CMASK ((1 << CSH) - 1)
#define CHUNK_E 8192           // edges per chunk block
#define CAP 4096               // max records per bucket (mean ~2048, 45 sigma)

__device__ __forceinline__ unsigned short f2bf(float f) {
    unsigned int u = __float_as_uint(f);
    u += 0x7FFFu + ((u >> 16) & 1u);   // round-to-nearest-even
    return (unsigned short)(u >> 16);
}
__device__ __forceinline__ float bf2f(unsigned short h) {
    return __uint_as_float((unsigned int)h << 16);
}

typedef __attribute__((ext_vector_type(8))) short bf16x8;
typedef __attribute__((ext_vector_type(4))) float f32x4;

// ---------- 1. GEMM via MFMA, 3-term bf16 split, fp32 accum ----------
__global__ __launch_bounds__(512) void gemm_mfma(
    const float* __restrict__ H, const float* __restrict__ Wg,
    unsigned short* __restrict__ Hpb, int N)
{
    __shared__ unsigned short Ahi[128 * 128];   // 32 KB each
    __shared__ unsigned short Alo[128 * 128];
    __shared__ unsigned short Whi[128 * 128];   // Wt[n][k]
    __shared__ unsigned short Wlo[128 * 128];
    const int tid = threadIdx.x;
    const int rbase = blockIdx.x * 128;

    #pragma unroll
    for (int i = 0; i < 4; ++i) {
        int task = tid + 512 * i;          // 2048 tasks
        int n  = task & 127;
        int k0 = (task >> 7) * 8;
        unsigned int hi[4], lo[4];
        #pragma unroll
        for (int j = 0; j < 4; ++j) {
            float w0 = Wg[(size_t)(k0 + 2*j)     * 128 + n];
            float w1 = Wg[(size_t)(k0 + 2*j + 1) * 128 + n];
            unsigned short h0 = f2bf(w0), h1 = f2bf(w1);
            unsigned short l0 = f2bf(w0 - bf2f(h0)), l1 = f2bf(w1 - bf2f(h1));
            hi[j] = (unsigned int)h0 | ((unsigned int)h1 << 16);
            lo[j] = (unsigned int)l0 | ((unsigned int)l1 << 16);
        }
        int byte = (k0 * 2) ^ ((n & 7) << 4);
        *(uint4*)((char*)Whi + n * 256 + byte) = make_uint4(hi[0], hi[1], hi[2], hi[3]);
        *(uint4*)((char*)Wlo + n * 256 + byte) = make_uint4(lo[0], lo[1], lo[2], lo[3]);
    }
    #pragma unroll
    for (int i = 0; i < 8; ++i) {
        int flat = tid + 512 * i;          // 4096 float4-tasks
        int row = flat >> 5;
        int c4  = (flat & 31) * 4;
        float4 h = make_float4(0.f, 0.f, 0.f, 0.f);
        if (rbase + row < N)
            h = *(const float4*)&H[(size_t)(rbase + row) * 128 + c4];
        unsigned short h0 = f2bf(h.x), h1 = f2bf(h.y), h2 = f2bf(h.z), h3 = f2bf(h.w);
        uint2 vh, vl;
        vh.x = (unsigned int)h0 | ((unsigned int)h1 << 16);
        vh.y = (unsigned int)h2 | ((unsigned int)h3 << 16);
        vl.x = (unsigned int)f2bf(h.x - bf2f(h0)) | ((unsigned int)f2bf(h.y - bf2f(h1)) << 16);
        vl.y = (unsigned int)f2bf(h.z - bf2f(h2)) | ((unsigned int)f2bf(h.w - bf2f(h3)) << 16);
        int byte = (c4 * 2) ^ ((row & 7) << 4);
        *(uint2*)((char*)Ahi + row * 256 + byte) = vh;
        *(uint2*)((char*)Alo + row * 256 + byte) = vl;
    }
    __syncthreads();

    const int wid = tid >> 6, lane = tid & 63;
    const int wm = wid >> 1, wn = wid & 1;
    const int lr = lane & 15, lg = lane >> 4;
    f32x4 acc[2][4] = {};

    #pragma unroll
    for (int ks = 0; ks < 4; ++ks) {
        const int kb = ks * 64 + lg * 16;
        bf16x8 ahi[2], alo[2];
        #pragma unroll
        for (int mi = 0; mi < 2; ++mi) {
            int row = wm * 32 + mi * 16 + lr;
            int sw = kb ^ ((row & 7) << 4);
            ahi[mi] = *(const bf16x8*)((char*)Ahi + row * 256 + sw);
            alo[mi] = *(const bf16x8*)((char*)Alo + row * 256 + sw);
        }
        #pragma unroll
        for (int nf = 0; nf < 4; ++nf) {
            int n = wn * 64 + nf * 16 + lr;
            int sw = kb ^ ((n & 7) << 4);
            bf16x8 bhi = *(const bf16x8*)((char*)Whi + n * 256 + sw);
            bf16x8 blo = *(const bf16x8*)((char*)Wlo + n * 256 + sw);
            #pragma unroll
            for (int mi = 0; mi < 2; ++mi) {
                acc[mi][nf] = __builtin_amdgcn_mfma_f32_16x16x32_bf16(ahi[mi], bhi, acc[mi][nf], 0, 0, 0);
                acc[mi][nf] = __builtin_amdgcn_mfma_f32_16x16x32_bf16(ahi[mi], blo, acc[mi][nf], 0, 0, 0);
                acc[mi][nf] = __builtin_amdgcn_mfma_f32_16x16x32_bf16(alo[mi], bhi, acc[mi][nf], 0, 0, 0);
            }
        }
    }

    #pragma unroll
    for (int mi = 0; mi < 2; ++mi) {
        #pragma unroll
        for (int nf = 0; nf < 4; ++nf) {
            int col = wn * 64 + nf * 16 + lr;
            #pragma unroll
            for (int i = 0; i < 4; ++i) {
                int row = rbase + wm * 32 + mi * 16 + lg * 4 + i;
                if (row < N)
                    Hpb[(size_t)row * 128 + col] = f2bf(acc[mi][nf][i]);
            }
        }
    }
}

// ---------- 2a. per-(chunk,bucket) histogram ----------
__global__ __launch_bounds__(256) void chunk_hist(
    const int* __restrict__ row, unsigned short* __restrict__ Ht,
    int E, int nchunk, int nb2)
{
    __shared__ int cnt[1024];
    const int tid = threadIdx.x;
    const int c = blockIdx.x;
    for (int i = tid; i < nb2; i += 256) cnt[i] = 0;
    __syncthreads();
    const int e0 = c * CHUNK_E;
    const int e1 = min(e0 + CHUNK_E, E);
    for (int e = e0 + tid; e < e1; e += 256)
        atomicAdd(&cnt[row[e] >> RSH], 1);
    __syncthreads();
    for (int i = tid; i < nb2; i += 256)
        Ht[(size_t)i * nchunk + c] = (unsigned short)cnt[i];
}

// ---------- 2b. per-bucket scan over chunks ----------
__global__ __launch_bounds__(256) void bucket_scan(
    const unsigned short* __restrict__ Ht, unsigned short* __restrict__ rel,
    int* __restrict__ totals, int nchunk)
{
    __shared__ int s[256];
    const int b = blockIdx.x, tid = threadIdx.x;
    int v = (tid < nchunk) ? (int)Ht[(size_t)b * nchunk + tid] : 0;
    s[tid] = v;
    __syncthreads();
    for (int d = 1; d < 256; d <<= 1) {
        int t = (tid >= d) ? s[tid - d] : 0;
        __syncthreads();
        s[tid] += t;
        __syncthreads();
    }
    if (tid < nchunk) rel[(size_t)b * nchunk + tid] = (unsigned short)(s[tid] - v);
    if (tid == 255) totals[b] = s[255];
}

// ---------- 2c. scan bucket totals -> bucketptr ----------
__global__ __launch_bounds__(1024) void bucket_ptr_scan(
    const int* __restrict__ totals, int* __restrict__ bucketptr, int nb2)
{
    __shared__ int s[1024];
    const int tid = threadIdx.x;
    int v = (tid < nb2) ? totals[tid] : 0;
    s[tid] = v;
    __syncthreads();
    for (int d = 1; d < 1024; d <<= 1) {
        int t = (tid >= d) ? s[tid - d] : 0;
        __syncthreads();
        s[tid] += t;
        __syncthreads();
    }
    if (tid < nb2) bucketptr[tid] = s[tid] - v;
    if (tid == nb2 - 1) bucketptr[nb2] = s[tid];
}

// ---------- 2d. atomic-free scatter: in-LDS counting sort by bucket ----------
__global__ __launch_bounds__(256) void chunk_scatter(
    const int* __restrict__ row, const int* __restrict__ col,
    const unsigned short* __restrict__ rel, const int* __restrict__ bucketptr,
    int* __restrict__ colsort, int E, int nchunk, int nb2)
{
    __shared__ int loc[1025];
    __shared__ int cur[1024];
    __shared__ int gb[1024];
    __shared__ unsigned short bid[CHUNK_E];
    __shared__ int ord[CHUNK_E];
    __shared__ int part[256];
    const int tid = threadIdx.x;
    const int c = blockIdx.x;
    const int e0 = c * CHUNK_E;
    const int tot = min(CHUNK_E, E - e0);

    for (int i = tid; i < nb2; i += 256) loc[i] = 0;
    __syncthreads();
    for (int j = tid; j < tot; j += 256)
        atomicAdd(&loc[row[e0 + j] >> RSH], 1);
    __syncthreads();

    const int base = tid * 4;
    int v[4]; int s = 0;
    #pragma unroll
    for (int i = 0; i < 4; ++i) {
        int idx = base + i;
        v[i] = (idx < nb2) ? loc[idx] : 0;
        s += v[i];
    }
    part[tid] = s;
    __syncthreads();
    for (int d = 1; d < 256; d <<= 1) {
        int t = (tid >= d) ? part[tid - d] : 0;
        __syncthreads();
        part[tid] += t;
        __syncthreads();
    }
    int run = part[tid] - s;
    #pragma unroll
    for (int i = 0; i < 4; ++i) {
        int idx = base + i;
        if (idx < nb2) { loc[idx] = run; cur[idx] = run; }
        run += v[i];
    }
    if (tid == 255) loc[nb2] = part[255];
    __syncthreads();

    for (int b = tid; b < nb2; b += 256) {
        gb[b] = bucketptr[b] + (int)rel[(size_t)b * nchunk + c];
        int st = loc[b], en = loc[b + 1];
        for (int j = st; j < en; ++j) bid[j] = (unsigned short)b;
    }
    __syncthreads();

    for (int j = tid; j < tot; j += 256) {
        int r = row[e0 + j], cc = col[e0 + j];
        int b = r >> RSH;
        int p = atomicAdd(&cur[b], 1);
        ord[p] = ((r & (RPB - 1)) << CSH) | cc;
    }
    __syncthreads();

    for (int j = tid; j < tot; j += 256) {
        int b = bid[j];
        colsort[gb[b] + (j - loc[b])] = ord[j];
    }
}

// ---------- 2e. per-bucket: derive rowptr + in-place row sort ----------
__global__ __launch_bounds__(256) void bucket_sort(
    const int* __restrict__ bucketptr, int* __restrict__ rowptr,
    int* __restrict__ colsort, int N)
{
    __shared__ int rcnt[RPB];
    __shared__ int rcur[RPB];
    __shared__ int sc[256];
    __shared__ int ord[CAP];
    const int b = blockIdx.x, tid = threadIdx.x;
    const int rbase = b << RSH;
    const int s0 = bucketptr[b];
    const int cnt = bucketptr[b + 1] - s0;

    if (tid < RPB) rcnt[tid] = 0;
    __syncthreads();
    for (int j = tid; j < cnt; j += 256)
        atomicAdd(&rcnt[colsort[s0 + j] >> CSH], 1);
    __syncthreads();

    int v = (tid < RPB) ? rcnt[tid] : 0;
    sc[tid] = v;
    __syncthreads();
    for (int d = 1; d < RPB; d <<= 1) {
        int t = (tid >= d) ? sc[tid - d] : 0;
        __syncthreads();
        sc[tid] += t;
        __syncthreads();
    }
    if (tid < RPB) {
        int ex = sc[tid] - v;
        rcur[tid] = ex;
        int r = rbase + tid;
        if (r < N) rowptr[r] = s0 + ex;
    }
    if (tid == RPB - 1) {
        int rend = min(rbase + RPB, N);
        rowptr[rend] = s0 + cnt;
    }
    __syncthreads();

    for (int j = tid; j < cnt; j += 256) {
        int rec = colsort[s0 + j];
        int p = atomicAdd(&rcur[rec >> CSH], 1);
        ord[p] = rec & CMASK;
    }
    __syncthreads();
    for (int j = tid; j < cnt; j += 256)
        colsort[s0 + j] = ord[j];
}

// ---------- 3. fused score + softmax + aggregate ----------
// Persistent groups: one row per 16-lane group, each group streams rows
// with stride ngroups. 4 groups/wave x unroll-2 = 8 independent chains.
__device__ __forceinline__ void unpack8(uint4 v, float* f) {
    f[0] = __uint_as_float(v.x << 16);
    f[1] = __uint_as_float(v.x & 0xFFFF0000u);
    f[2] = __uint_as_float(v.y << 16);
    f[3] = __uint_as_float(v.y & 0xFFFF0000u);
    f[4] = __uint_as_float(v.z << 16);
    f[5] = __uint_as_float(v.z & 0xFFFF0000u);
    f[6] = __uint_as_float(v.w << 16);
    f[7] = __uint_as_float(v.w & 0xFFFF0000u);
}

__global__ __launch_bounds__(256) void aggregate_kernel(
    const unsigned short* __restrict__ Hpb, const int* __restrict__ rowptr,
    const int* __restrict__ cols, const float* __restrict__ bias,
    float* __restrict__ out, int N, int ngroups)
{
    const int lane = threadIdx.x & 63;
    const int wv   = threadIdx.x >> 6;
    const int g = lane >> 4;
    const int d = lane & 15;
    const int gid0 = (blockIdx.x * 4 + wv) * 4 + g;

    const float4* bp = (const float4*)&bias[d * 8];
    const float4 b0 = bp[0], b1 = bp[1];

    for (int r = gid0; r < N; r += ngroups) {
        float hr[8];
        unpack8(*(const uint4*)&Hpb[(size_t)r * 128 + d * 8], hr);

        float acc[8] = {0.f,0.f,0.f,0.f,0.f,0.f,0.f,0.f};
        float den = 0.f;
        int e = rowptr[r];
        const int e1 = rowptr[r + 1];

        for (; e + 1 < e1; e += 2) {
            int c0 = cols[e];
            int c1 = cols[e + 1];
            uint4 v0 = *(const uint4*)&Hpb[(size_t)c0 * 128 + d * 8];
            uint4 v1 = *(const uint4*)&Hpb[(size_t)c1 * 128 + d * 8];
            float hc0[8], hc1[8];
            unpack8(v0, hc0);
            unpack8(v1, hc1);
            float dot0 = hr[0]*hc0[0] + hr[1]*hc0[1] + hr[2]*hc0[2] + hr[3]*hc0[3]
                       + hr[4]*hc0[4] + hr[5]*hc0[5] + hr[6]*hc0[6] + hr[7]*hc0[7];
            float dot1 = hr[0]*hc1[0] + hr[1]*hc1[1] + hr[2]*hc1[2] + hr[3]*hc1[3]
                       + hr[4]*hc1[4] + hr[5]*hc1[5] + hr[6]*hc1[6] + hr[7]*hc1[7];
            dot0 += __shfl_xor(dot0, 1);
            dot1 += __shfl_xor(dot1, 1);
            dot0 += __shfl_xor(dot0, 2);
            dot1 += __shfl_xor(dot1, 2);
            dot0 += __shfl_xor(dot0, 4);
            dot1 += __shfl_xor(dot1, 4);
            dot0 += __shfl_xor(dot0, 8);
            dot1 += __shfl_xor(dot1, 8);
            float s0 = dot0 > 0.f ? dot0 : 0.2f * dot0;
            float s1 = dot1 > 0.f ? dot1 : 0.2f * dot1;
            float ex0 = __expf(s0);
            float ex1 = __expf(s1);
            den += ex0 + ex1;
            #pragma unroll
            for (int k = 0; k < 8; ++k) {
                acc[k] = fmaf(ex0, hc0[k], acc[k]);
                acc[k] = fmaf(ex1, hc1[k], acc[k]);
            }
        }
        if (e < e1) {
            int c = cols[e];
            float hc[8];
            unpack8(*(const uint4*)&Hpb[(size_t)c * 128 + d * 8], hc);
            float dot = hr[0]*hc[0] + hr[1]*hc[1] + hr[2]*hc[2] + hr[3]*hc[3]
                      + hr[4]*hc[4] + hr[5]*hc[5] + hr[6]*hc[6] + hr[7]*hc[7];
            dot += __shfl_xor(dot, 1);
            dot += __shfl_xor(dot, 2);
            dot += __shfl_xor(dot, 4);
            dot += __shfl_xor(dot, 8);
            float s  = dot > 0.f ? dot : 0.2f * dot;
            float ex = __expf(s);
            den += ex;
            #pragma unroll
            for (int k = 0; k < 8; ++k)
                acc[k] = fmaf(ex, hc[k], acc[k]);
        }

        float inv = 1.f / (den + 1e-10f);
        float4 o0, o1;
        o0.x = fmaf(acc[0], inv, b0.x);
        o0.y = fmaf(acc[1], inv, b0.y);
        o0.z = fmaf(acc[2], inv, b0.z);
        o0.w = fmaf(acc[3], inv, b0.w);
        o1.x = fmaf(acc[4], inv, b1.x);
        o1.y = fmaf(acc[5], inv, b1.y);
        o1.z = fmaf(acc[6], inv, b1.z);
        o1.w = fmaf(acc[7], inv, b1.w);
        float4* op = (float4*)&out[(size_t)r * 128 + d * 8];
        op[0] = o0;
        op[1] = o1;
    }
}

extern "C" void kernel_launch(void* const* d_in, const int* in_sizes, int n_in,
                              void* d_out, int out_size, void* d_ws, size_t ws_size,
                              hipStream_t stream)
{
    const float* H    = (const float*)d_in[0];
    const float* W    = (const float*)d_in[1];
    const float* bias = (const float*)d_in[2];
    const int*   row  = (const int*)d_in[3];
    const int*   col  = (const int*)d_in[4];
    const int N = in_sizes[0] / 128;
    const int E = in_sizes[3];

    const int nchunk = (E + CHUNK_E - 1) / CHUNK_E;   // 196
    const int nb2    = (N + RPB - 1) / RPB;           // 782

    auto align = [](size_t x) { return (x + 255) & ~(size_t)255; };

    char* ws = (char*)d_ws;
    size_t off = 0;
    unsigned short* Hpb       = (unsigned short*)(ws + off); off = align(off + (size_t)N * 128 * 2);
    unsigned short* Ht        = (unsigned short*)(ws + off); off = align(off + (size_t)nb2 * nchunk * 2);
    unsigned short* rel       = (unsigned short*)(ws + off); off = align(off + (size_t)nb2 * nchunk * 2);
    int*            totals    = (int*)(ws + off);            off = align(off + (size_t)nb2 * 4);
    int*            bucketptr = (int*)(ws + off);            off = align(off + (size_t)(nb2 + 1) * 4);
    int*            rowptr    = (int*)(ws + off);            off = align(off + (size_t)(N + 1) * 4);
    int*            colsort   = (int*)(ws + off);

    gemm_mfma<<<(N + 127) / 128, 512, 0, stream>>>(H, W, Hpb, N);
    chunk_hist<<<nchunk, 256, 0, stream>>>(row, Ht, E, nchunk, nb2);
    bucket_scan<<<nb2, 256, 0, stream>>>(Ht, rel, totals, nchunk);
    bucket_ptr_scan<<<1, 1024, 0, stream>>>(totals, bucketptr, nb2);
    chunk_scatter<<<nchunk, 256, 0, stream>>>(row, col, rel, bucketptr,
                                              colsort, E, nchunk, nb2);
    bucket_sort<<<nb2, 256, 0, stream>>>(bucketptr, rowptr, colsort, N);

    const int AGG_BLOCKS = 2048;                       // 32 waves/CU capacity
    aggregate_kernel<<<AGG_BLOCKS, 256, 0, stream>>>(Hpb, rowptr, colsort, bias,
                                                     (float*)d_out, N,
                                                     AGG_BLOCKS * 16);
}

// Round 11
// 141.993 us; speedup vs baseline: 1.1500x; 1.1500x over previous
//
#include <hip/hip_runtime.h>
#include <hip/hip_bf16.h>

#define RSH 7                  // 128 rows per bucket
#define RPB (1 << RSH)
#define CSH 17                 // col bits in packed record (N < 131072)
#define CMASK ((1 << CSH) - 1)
#define CHUNK_E 8192           // edges per chunk block
#define CAP 4096               // max records per bucket (mean ~2048, 45 sigma)

__device__ __forceinline__ unsigned short f2bf(float f) {
    unsigned int u = __float_as_uint(f);
    u += 0x7FFFu + ((u >> 16) & 1u);   // round-to-nearest-even
    return (unsigned short)(u >> 16);
}
__device__ __forceinline__ float bf2f(unsigned short h) {
    return __uint_as_float((unsigned int)h << 16);
}

typedef __attribute__((ext_vector_type(8))) short bf16x8;
typedef __attribute__((ext_vector_type(4))) float f32x4;
typedef __attribute__((ext_vector_type(2))) float f32x2;

// ---------- 1. fused: GEMM via MFMA (blocks < gemmBlocks) + chunk_hist ----------
__global__ __launch_bounds__(512) void gemm_hist(
    const float* __restrict__ H, const float* __restrict__ Wg,
    unsigned short* __restrict__ Hpb, int N,
    const int* __restrict__ row, unsigned short* __restrict__ Ht,
    int E, int nchunk, int nb2, int gemmBlocks)
{
    __shared__ unsigned short Ahi[128 * 128];   // 32 KB each
    __shared__ unsigned short Alo[128 * 128];
    __shared__ unsigned short Whi[128 * 128];   // Wt[n][k]
    __shared__ unsigned short Wlo[128 * 128];
    const int tid = threadIdx.x;

    if (blockIdx.x >= gemmBlocks) {
        // ---- histogram role (reuses Ahi as int counts) ----
        int* cnt = (int*)Ahi;
        const int c = blockIdx.x - gemmBlocks;
        for (int i = tid; i < nb2; i += 512) cnt[i] = 0;
        __syncthreads();
        const int e0 = c * CHUNK_E;
        const int e1 = min(e0 + CHUNK_E, E);
        for (int e = e0 + tid; e < e1; e += 512)
            atomicAdd(&cnt[row[e] >> RSH], 1);
        __syncthreads();
        for (int i = tid; i < nb2; i += 512)
            Ht[(size_t)i * nchunk + c] = (unsigned short)cnt[i];
        return;
    }

    const int rbase = blockIdx.x * 128;

    #pragma unroll
    for (int i = 0; i < 4; ++i) {
        int task = tid + 512 * i;          // 2048 tasks
        int n  = task & 127;
        int k0 = (task >> 7) * 8;
        unsigned int hi[4], lo[4];
        #pragma unroll
        for (int j = 0; j < 4; ++j) {
            float w0 = Wg[(size_t)(k0 + 2*j)     * 128 + n];
            float w1 = Wg[(size_t)(k0 + 2*j + 1) * 128 + n];
            unsigned short h0 = f2bf(w0), h1 = f2bf(w1);
            unsigned short l0 = f2bf(w0 - bf2f(h0)), l1 = f2bf(w1 - bf2f(h1));
            hi[j] = (unsigned int)h0 | ((unsigned int)h1 << 16);
            lo[j] = (unsigned int)l0 | ((unsigned int)l1 << 16);
        }
        int byte = (k0 * 2) ^ ((n & 7) << 4);
        *(uint4*)((char*)Whi + n * 256 + byte) = make_uint4(hi[0], hi[1], hi[2], hi[3]);
        *(uint4*)((char*)Wlo + n * 256 + byte) = make_uint4(lo[0], lo[1], lo[2], lo[3]);
    }
    #pragma unroll
    for (int i = 0; i < 8; ++i) {
        int flat = tid + 512 * i;          // 4096 float4-tasks
        int rr = flat >> 5;
        int c4  = (flat & 31) * 4;
        float4 h = make_float4(0.f, 0.f, 0.f, 0.f);
        if (rbase + rr < N)
            h = *(const float4*)&H[(size_t)(rbase + rr) * 128 + c4];
        unsigned short h0 = f2bf(h.x), h1 = f2bf(h.y), h2 = f2bf(h.z), h3 = f2bf(h.w);
        uint2 vh, vl;
        vh.x = (unsigned int)h0 | ((unsigned int)h1 << 16);
        vh.y = (unsigned int)h2 | ((unsigned int)h3 << 16);
        vl.x = (unsigned int)f2bf(h.x - bf2f(h0)) | ((unsigned int)f2bf(h.y - bf2f(h1)) << 16);
        vl.y = (unsigned int)f2bf(h.z - bf2f(h2)) | ((unsigned int)f2bf(h.w - bf2f(h3)) << 16);
        int byte = (c4 * 2) ^ ((rr & 7) << 4);
        *(uint2*)((char*)Ahi + rr * 256 + byte) = vh;
        *(uint2*)((char*)Alo + rr * 256 + byte) = vl;
    }
    __syncthreads();

    const int wid = tid >> 6, lane = tid & 63;
    const int wm = wid >> 1, wn = wid & 1;
    const int lr = lane & 15, lg = lane >> 4;
    f32x4 acc[2][4] = {};

    #pragma unroll
    for (int ks = 0; ks < 4; ++ks) {
        const int kb = ks * 64 + lg * 16;
        bf16x8 ahi[2], alo[2];
        #pragma unroll
        for (int mi = 0; mi < 2; ++mi) {
            int rr = wm * 32 + mi * 16 + lr;
            int sw = kb ^ ((rr & 7) << 4);
            ahi[mi] = *(const bf16x8*)((char*)Ahi + rr * 256 + sw);
            alo[mi] = *(const bf16x8*)((char*)Alo + rr * 256 + sw);
        }
        #pragma unroll
        for (int nf = 0; nf < 4; ++nf) {
            int n = wn * 64 + nf * 16 + lr;
            int sw = kb ^ ((n & 7) << 4);
            bf16x8 bhi = *(const bf16x8*)((char*)Whi + n * 256 + sw);
            bf16x8 blo = *(const bf16x8*)((char*)Wlo + n * 256 + sw);
            #pragma unroll
            for (int mi = 0; mi < 2; ++mi) {
                acc[mi][nf] = __builtin_amdgcn_mfma_f32_16x16x32_bf16(ahi[mi], bhi, acc[mi][nf], 0, 0, 0);
                acc[mi][nf] = __builtin_amdgcn_mfma_f32_16x16x32_bf16(ahi[mi], blo, acc[mi][nf], 0, 0, 0);
                acc[mi][nf] = __builtin_amdgcn_mfma_f32_16x16x32_bf16(alo[mi], bhi, acc[mi][nf], 0, 0, 0);
            }
        }
    }

    #pragma unroll
    for (int mi = 0; mi < 2; ++mi) {
        #pragma unroll
        for (int nf = 0; nf < 4; ++nf) {
            int col = wn * 64 + nf * 16 + lr;
            #pragma unroll
            for (int i = 0; i < 4; ++i) {
                int rr = rbase + wm * 32 + mi * 16 + lg * 4 + i;
                if (rr < N)
                    Hpb[(size_t)rr * 128 + col] = f2bf(acc[mi][nf][i]);
            }
        }
    }
}

// ---------- 2b. per-bucket scan over chunks ----------
__global__ __launch_bounds__(256) void bucket_scan(
    const unsigned short* __restrict__ Ht, unsigned short* __restrict__ rel,
    int* __restrict__ totals, int nchunk)
{
    __shared__ int s[256];
    const int b = blockIdx.x, tid = threadIdx.x;
    int v = (tid < nchunk) ? (int)Ht[(size_t)b * nchunk + tid] : 0;
    s[tid] = v;
    __syncthreads();
    for (int d = 1; d < 256; d <<= 1) {
        int t = (tid >= d) ? s[tid - d] : 0;
        __syncthreads();
        s[tid] += t;
        __syncthreads();
    }
    if (tid < nchunk) rel[(size_t)b * nchunk + tid] = (unsigned short)(s[tid] - v);
    if (tid == 255) totals[b] = s[255];
}

// ---------- 2c. scan bucket totals -> bucketptr ----------
__global__ __launch_bounds__(1024) void bucket_ptr_scan(
    const int* __restrict__ totals, int* __restrict__ bucketptr, int nb2)
{
    __shared__ int s[1024];
    const int tid = threadIdx.x;
    int v = (tid < nb2) ? totals[tid] : 0;
    s[tid] = v;
    __syncthreads();
    for (int d = 1; d < 1024; d <<= 1) {
        int t = (tid >= d) ? s[tid - d] : 0;
        __syncthreads();
        s[tid] += t;
        __syncthreads();
    }
    if (tid < nb2) bucketptr[tid] = s[tid] - v;
    if (tid == nb2 - 1) bucketptr[nb2] = s[tid];
}

// ---------- 2d. atomic-free scatter: in-LDS counting sort by bucket ----------
__global__ __launch_bounds__(256) void chunk_scatter(
    const int* __restrict__ row, const int* __restrict__ col,
    const unsigned short* __restrict__ rel, const int* __restrict__ bucketptr,
    int* __restrict__ colsort, int E, int nchunk, int nb2)
{
    __shared__ int loc[1025];
    __shared__ int cur[1024];
    __shared__ int gb[1024];
    __shared__ unsigned short bid[CHUNK_E];
    __shared__ int ord[CHUNK_E];
    __shared__ int part[256];
    const int tid = threadIdx.x;
    const int c = blockIdx.x;
    const int e0 = c * CHUNK_E;
    const int tot = min(CHUNK_E, E - e0);

    for (int i = tid; i < nb2; i += 256) loc[i] = 0;
    __syncthreads();
    for (int j = tid; j < tot; j += 256)
        atomicAdd(&loc[row[e0 + j] >> RSH], 1);
    __syncthreads();

    const int base = tid * 4;
    int v[4]; int s = 0;
    #pragma unroll
    for (int i = 0; i < 4; ++i) {
        int idx = base + i;
        v[i] = (idx < nb2) ? loc[idx] : 0;
        s += v[i];
    }
    part[tid] = s;
    __syncthreads();
    for (int d = 1; d < 256; d <<= 1) {
        int t = (tid >= d) ? part[tid - d] : 0;
        __syncthreads();
        part[tid] += t;
        __syncthreads();
    }
    int run = part[tid] - s;
    #pragma unroll
    for (int i = 0; i < 4; ++i) {
        int idx = base + i;
        if (idx < nb2) { loc[idx] = run; cur[idx] = run; }
        run += v[i];
    }
    if (tid == 255) loc[nb2] = part[255];
    __syncthreads();

    for (int b = tid; b < nb2; b += 256) {
        gb[b] = bucketptr[b] + (int)rel[(size_t)b * nchunk + c];
        int st = loc[b], en = loc[b + 1];
        for (int j = st; j < en; ++j) bid[j] = (unsigned short)b;
    }
    __syncthreads();

    for (int j = tid; j < tot; j += 256) {
        int r = row[e0 + j], cc = col[e0 + j];
        int b = r >> RSH;
        int p = atomicAdd(&cur[b], 1);
        ord[p] = ((r & (RPB - 1)) << CSH) | cc;
    }
    __syncthreads();

    for (int j = tid; j < tot; j += 256) {
        int b = bid[j];
        colsort[gb[b] + (j - loc[b])] = ord[j];
    }
}

// ---------- 2e. per-bucket: derive rowptr + in-place row sort ----------
__global__ __launch_bounds__(256) void bucket_sort(
    const int* __restrict__ bucketptr, int* __restrict__ rowptr,
    int* __restrict__ colsort, int N)
{
    __shared__ int rcnt[RPB];
    __shared__ int rcur[RPB];
    __shared__ int sc[256];
    __shared__ int ord[CAP];
    const int b = blockIdx.x, tid = threadIdx.x;
    const int rbase = b << RSH;
    const int s0 = bucketptr[b];
    const int cnt = bucketptr[b + 1] - s0;

    if (tid < RPB) rcnt[tid] = 0;
    __syncthreads();
    for (int j = tid; j < cnt; j += 256)
        atomicAdd(&rcnt[colsort[s0 + j] >> CSH], 1);
    __syncthreads();

    int v = (tid < RPB) ? rcnt[tid] : 0;
    sc[tid] = v;
    __syncthreads();
    for (int d = 1; d < RPB; d <<= 1) {
        int t = (tid >= d) ? sc[tid - d] : 0;
        __syncthreads();
        sc[tid] += t;
        __syncthreads();
    }
    if (tid < RPB) {
        int ex = sc[tid] - v;
        rcur[tid] = ex;
        int r = rbase + tid;
        if (r < N) rowptr[r] = s0 + ex;
    }
    if (tid == RPB - 1) {
        int rend = min(rbase + RPB, N);
        rowptr[rend] = s0 + cnt;
    }
    __syncthreads();

    for (int j = tid; j < cnt; j += 256) {
        int rec = colsort[s0 + j];
        int p = atomicAdd(&rcur[rec >> CSH], 1);
        ord[p] = rec & CMASK;
    }
    __syncthreads();
    for (int j = tid; j < cnt; j += 256)
        colsort[s0 + j] = ord[j];
}

// ---------- 3. fused score + softmax + aggregate ----------
// Wave-per-row (R9 structure), 4 groups split edges stride-4, unroll-2 with
// mask-predicated second chain (no divergent tail), f32x2 packed math.
__device__ __forceinline__ void unpack8v(uint4 v, f32x2* p) {
    p[0] = (f32x2){__uint_as_float(v.x << 16), __uint_as_float(v.x & 0xFFFF0000u)};
    p[1] = (f32x2){__uint_as_float(v.y << 16), __uint_as_float(v.y & 0xFFFF0000u)};
    p[2] = (f32x2){__uint_as_float(v.z << 16), __uint_as_float(v.z & 0xFFFF0000u)};
    p[3] = (f32x2){__uint_as_float(v.w << 16), __uint_as_float(v.w & 0xFFFF0000u)};
}

__global__ __launch_bounds__(256) void aggregate_kernel(
    const unsigned short* __restrict__ Hpb, const int* __restrict__ rowptr,
    const int* __restrict__ cols, const float* __restrict__ bias,
    float* __restrict__ out, int N)
{
    const int lane = threadIdx.x & 63;
    const int wv   = threadIdx.x >> 6;
    const int r = blockIdx.x * 4 + wv;
    if (r >= N) return;
    const int d = lane & 15;
    const int g = lane >> 4;

    const float4* bp = (const float4*)&bias[d * 8];
    const float4 b0 = bp[0], b1 = bp[1];

    f32x2 hr2[4];
    unpack8v(*(const uint4*)&Hpb[(size_t)r * 128 + d * 8], hr2);

    f32x2 acc2[4] = {};
    float den = 0.f;
    const int e0 = rowptr[r], e1 = rowptr[r + 1];
    const int elast = e1 - 1;

    for (int e = e0 + g; e < e1; e += 8) {
        const bool m1 = (e + 4 < e1);
        const int ea = e;
        const int eb = m1 ? e + 4 : elast;
        int c0 = cols[ea];
        int c1 = cols[eb];
        uint4 v0 = *(const uint4*)&Hpb[(size_t)c0 * 128 + d * 8];
        uint4 v1 = *(const uint4*)&Hpb[(size_t)c1 * 128 + d * 8];
        f32x2 hc0[4], hc1[4];
        unpack8v(v0, hc0);
        unpack8v(v1, hc1);

        f32x2 dp0 = hr2[0] * hc0[0];
        f32x2 dp1 = hr2[0] * hc1[0];
        dp0 += hr2[1] * hc0[1];
        dp1 += hr2[1] * hc1[1];
        dp0 += hr2[2] * hc0[2];
        dp1 += hr2[2] * hc1[2];
        dp0 += hr2[3] * hc0[3];
        dp1 += hr2[3] * hc1[3];
        float dot0 = dp0.x + dp0.y;
        float dot1 = dp1.x + dp1.y;

        dot0 += __shfl_xor(dot0, 1);
        dot1 += __shfl_xor(dot1, 1);
        dot0 += __shfl_xor(dot0, 2);
        dot1 += __shfl_xor(dot1, 2);
        dot0 += __shfl_xor(dot0, 4);
        dot1 += __shfl_xor(dot1, 4);
        dot0 += __shfl_xor(dot0, 8);
        dot1 += __shfl_xor(dot1, 8);

        float s0 = fmaxf(dot0, 0.2f * dot0);
        float s1 = fmaxf(dot1, 0.2f * dot1);
        float ex0 = __expf(s0);
        float ex1 = m1 ? __expf(s1) : 0.f;
        den += ex0 + ex1;
        #pragma unroll
        for (int k = 0; k < 4; ++k) {
            acc2[k] += hc0[k] * ex0;
            acc2[k] += hc1[k] * ex1;
        }
    }

    #pragma unroll
    for (int k = 0; k < 4; ++k) {
        acc2[k].x += __shfl_xor(acc2[k].x, 16);
        acc2[k].y += __shfl_xor(acc2[k].y, 16);
        acc2[k].x += __shfl_xor(acc2[k].x, 32);
        acc2[k].y += __shfl_xor(acc2[k].y, 32);
    }
    den += __shfl_xor(den, 16);
    den += __shfl_xor(den, 32);

    if (g == 0) {
        float inv = 1.f / (den + 1e-10f);
        float4 o0, o1;
        o0.x = fmaf(acc2[0].x, inv, b0.x);
        o0.y = fmaf(acc2[0].y, inv, b0.y);
        o0.z = fmaf(acc2[1].x, inv, b0.z);
        o0.w = fmaf(acc2[1].y, inv, b0.w);
        o1.x = fmaf(acc2[2].x, inv, b1.x);
        o1.y = fmaf(acc2[2].y, inv, b1.y);
        o1.z = fmaf(acc2[3].x, inv, b1.z);
        o1.w = fmaf(acc2[3].y, inv, b1.w);
        float4* op = (float4*)&out[(size_t)r * 128 + d * 8];
        op[0] = o0;
        op[1] = o1;
    }
}

extern "C" void kernel_launch(void* const* d_in, const int* in_sizes, int n_in,
                              void* d_out, int out_size, void* d_ws, size_t ws_size,
                              hipStream_t stream)
{
    const float* H    = (const float*)d_in[0];
    const float* W    = (const float*)d_in[1];
    const float* bias = (const float*)d_in[2];
    const int*   row  = (const int*)d_in[3];
    const int*   col  = (const int*)d_in[4];
    const int N = in_sizes[0] / 128;
    const int E = in_sizes[3];

    const int nchunk = (E + CHUNK_E - 1) / CHUNK_E;   // 196
    const int nb2    = (N + RPB - 1) / RPB;           // 782

    auto align = [](size_t x) { return (x + 255) & ~(size_t)255; };

    char* ws = (char*)d_ws;
    size_t off = 0;
    unsigned short* Hpb       = (unsigned short*)(ws + off); off = align(off + (size_t)N * 128 * 2);
    unsigned short* Ht        = (unsigned short*)(ws + off); off = align(off + (size_t)nb2 * nchunk * 2);
    unsigned short* rel       = (unsigned short*)(ws + off); off = align(off + (size_t)nb2 * nchunk * 2);
    int*            totals    = (int*)(ws + off);            off = align(off + (size_t)nb2 * 4);
    int*            bucketptr = (int*)(ws + off);            off = align(off + (size_t)(nb2 + 1) * 4);
    int*            rowptr    = (int*)(ws + off);            off = align(off + (size_t)(N + 1) * 4);
    int*            colsort   = (int*)(ws + off);

    const int gemmBlocks = (N + 127) / 128;

    gemm_hist<<<gemmBlocks + nchunk, 512, 0, stream>>>(H, W, Hpb, N,
                                                       row, Ht, E, nchunk, nb2,
                                                       gemmBlocks);
    bucket_scan<<<nb2, 256, 0, stream>>>(Ht, rel, totals, nchunk);
    bucket_ptr_scan<<<1, 1024, 0, stream>>>(totals, bucketptr, nb2);
    chunk_scatter<<<nchunk, 256, 0, stream>>>(row, col, rel, bucketptr,
                                              colsort, E, nchunk, nb2);
    bucket_sort<<<nb2, 256, 0, stream>>>(bucketptr, rowptr, colsort, N);
    aggregate_kernel<<<(N + 3) / 4, 256, 0, stream>>>(Hpb, rowptr, colsort, bias,
                                                      (float*)d_out, N);
}